// Round 17
// baseline (6083.794 us; speedup 1.0000x reference)
//
#include <hip/hip_runtime.h>
#include <stdint.h>

#define HIST 1792
#define TGT 256
#define SEQ 2048
#define INPUT 352
#define EHID 250
#define HID 500

typedef _Float16 h2_t __attribute__((ext_vector_type(2)));

static __device__ __forceinline__ float fdot2(uint32_t a, uint32_t b, float c) {
  return __builtin_amdgcn_fdot2(__builtin_bit_cast(h2_t, a),
                                __builtin_bit_cast(h2_t, b), c, false);
}
static __device__ __forceinline__ uint32_t packh2(float lo, float hi) {
  h2_t h; h[0] = (_Float16)lo; h[1] = (_Float16)hi;
  return __builtin_bit_cast(uint32_t, h);
}
static __device__ __forceinline__ uint4 packq(const float* p) {
  uint4 r;
  r.x = packh2(p[0], p[1]); r.y = packh2(p[2], p[3]);
  r.z = packh2(p[4], p[5]); r.w = packh2(p[6], p[7]);
  return r;
}
static __device__ __forceinline__ float dotq(uint4 w, uint4 h, float acc) {
  acc = fdot2(w.x, h.x, acc); acc = fdot2(w.y, h.y, acc);
  acc = fdot2(w.z, h.z, acc); acc = fdot2(w.w, h.w, acc);
  return acc;
}
static __device__ __forceinline__ float sigf(float x) {
  x = fminf(fmaxf(x, -30.f), 30.f);
  return 1.f / (1.f + __expf(-x));
}
static __device__ __forceinline__ float tanh_f(float x) {
  x = fminf(fmaxf(x, -15.f), 15.f);
  float e = __expf(2.f * x);
  return (e - 1.f) / (e + 1.f);
}
static __device__ __forceinline__ void spin_flag(volatile int* f) {
  while (__hip_atomic_load(f, __ATOMIC_ACQUIRE, __HIP_MEMORY_SCOPE_AGENT) == 0)
    __builtin_amdgcn_s_sleep(2);
}
static __device__ __forceinline__ void spin_cnt(volatile int* f, int target) {
  while (__hip_atomic_load(f, __ATOMIC_ACQUIRE, __HIP_MEMORY_SCOPE_AGENT) < target)
    __builtin_amdgcn_s_sleep(2);
}
#define AW(dst, src) asm("v_accvgpr_write_b32 %0, %1" : "=a"(dst) : "v"(src))
#define AR(dst, src) asm("v_accvgpr_read_b32 %0, %1" : "=v"(dst) : "a"(src))
#define ARQ(dst, arr, base) do { AR(dst.x, arr[(base)+0]); AR(dst.y, arr[(base)+1]); AR(dst.z, arr[(base)+2]); AR(dst.w, arr[(base)+3]); } while(0)

// ---- in-fused input GEMM tile: A = embeddings gathered on the fly ----
static __device__ void gemm_tile_emb(const int* __restrict__ loc, const int* __restrict__ tim,
                                     const int* __restrict__ cid,
                                     const float* __restrict__ weight,
                                     const float* __restrict__ emb_tim_w,
                                     const float* __restrict__ weight_cid,
                                     int rowoff,
                                     const float* __restrict__ W,
                                     const float* __restrict__ bias,
                                     float* __restrict__ C, int ldc,
                                     int M, int N, int bm, int bn, int revA,
                                     int tid, uint32_t* AsP, uint32_t* WsP) {
  const int tx = tid & 15, ty = (tid & 255) >> 4;
  float acc[4][4] = {};
  for (int k0 = 0; k0 < INPUT; k0 += 16) {
    {
      int m = tid & 63, kk = tid >> 6;
      int gm = bm + m, gk = k0 + 2 * kk;
      float v0 = 0.f, v1 = 0.f;
      if (gm < M) {
        int am = (revA ? (M - 1 - gm) : gm) + rowoff;
        if (gk < 256) {
          const float* wp = weight + (size_t)loc[am] * 256 + gk;
          v0 = wp[0]; v1 = wp[1];
        } else if (gk < 288) {
          const float* wp = emb_tim_w + tim[am] * 32 + (gk - 256);
          v0 = wp[0]; v1 = wp[1];
        } else {
          const float* wp = weight_cid + cid[am] * 64 + (gk - 288);
          v0 = wp[0]; v1 = wp[1];
        }
      }
      AsP[kk * 65 + m] = packh2(v0, v1);
      int gn = bn + m;
      float w0 = 0.f, w1 = 0.f;
      if (gn < N) {
        const float* wp = W + (size_t)gn * INPUT + gk;
        w0 = wp[0]; w1 = wp[1];
      }
      WsP[kk * 65 + m] = packh2(w0, w1);
    }
    __syncthreads();
    if (tid < 256) {
#pragma unroll
      for (int kk = 0; kk < 8; kk++) {
        uint32_t a0 = AsP[kk * 65 + ty * 4 + 0], a1 = AsP[kk * 65 + ty * 4 + 1];
        uint32_t a2 = AsP[kk * 65 + ty * 4 + 2], a3 = AsP[kk * 65 + ty * 4 + 3];
        uint32_t b0 = WsP[kk * 65 + tx * 4 + 0], b1 = WsP[kk * 65 + tx * 4 + 1];
        uint32_t b2 = WsP[kk * 65 + tx * 4 + 2], b3 = WsP[kk * 65 + tx * 4 + 3];
        acc[0][0] = fdot2(a0, b0, acc[0][0]); acc[0][1] = fdot2(a0, b1, acc[0][1]);
        acc[0][2] = fdot2(a0, b2, acc[0][2]); acc[0][3] = fdot2(a0, b3, acc[0][3]);
        acc[1][0] = fdot2(a1, b0, acc[1][0]); acc[1][1] = fdot2(a1, b1, acc[1][1]);
        acc[1][2] = fdot2(a1, b2, acc[1][2]); acc[1][3] = fdot2(a1, b3, acc[1][3]);
        acc[2][0] = fdot2(a2, b0, acc[2][0]); acc[2][1] = fdot2(a2, b1, acc[2][1]);
        acc[2][2] = fdot2(a2, b2, acc[2][2]); acc[2][3] = fdot2(a2, b3, acc[2][3]);
        acc[3][0] = fdot2(a3, b0, acc[3][0]); acc[3][1] = fdot2(a3, b1, acc[3][1]);
        acc[3][2] = fdot2(a3, b2, acc[3][2]); acc[3][3] = fdot2(a3, b3, acc[3][3]);
      }
    }
    __syncthreads();
  }
  if (tid < 256) {
    for (int i = 0; i < 4; i++) {
      int gm = bm + ty * 4 + i; if (gm >= M) continue;
      for (int j = 0; j < 4; j++) {
        int gn = bn + tx * 4 + j; if (gn >= N) continue;
        C[(size_t)gm * ldc + gn] = acc[i][j] + bias[gn];
      }
    }
  }
}

// ---- NN GEMM tile (C = A@B + addvec), 512-stage/256-compute ----
static __device__ void nn_tile_fused(const float* __restrict__ A, int lda,
                                     const float* __restrict__ B, int ldb,
                                     const float* __restrict__ addvec,
                                     float* __restrict__ C, int ldc,
                                     int M, int N, int K, int bm, int bn,
                                     int tid, uint32_t* AsP, uint32_t* BsP) {
  const int tx = tid & 15, ty = (tid & 255) >> 4;
  float acc[4][4] = {};
  for (int k0 = 0; k0 < K; k0 += 16) {
    {
      int m = tid & 63, kk = tid >> 6;
      int gm = bm + m, gk = k0 + 2 * kk;
      float v0 = 0.f, v1 = 0.f;
      if (gm < M) {
        if (gk < K)     v0 = A[(size_t)gm * lda + gk];
        if (gk + 1 < K) v1 = A[(size_t)gm * lda + gk + 1];
      }
      AsP[kk * 65 + m] = packh2(v0, v1);
      int gn = bn + m;
      float w0 = 0.f, w1 = 0.f;
      if (gn < N) {
        if (gk < K)     w0 = B[(size_t)gk * ldb + gn];
        if (gk + 1 < K) w1 = B[(size_t)(gk + 1) * ldb + gn];
      }
      BsP[kk * 65 + m] = packh2(w0, w1);
    }
    __syncthreads();
    if (tid < 256) {
#pragma unroll
      for (int kk = 0; kk < 8; kk++) {
        uint32_t a0 = AsP[kk * 65 + ty * 4 + 0], a1 = AsP[kk * 65 + ty * 4 + 1];
        uint32_t a2 = AsP[kk * 65 + ty * 4 + 2], a3 = AsP[kk * 65 + ty * 4 + 3];
        uint32_t b0 = BsP[kk * 65 + tx * 4 + 0], b1 = BsP[kk * 65 + tx * 4 + 1];
        uint32_t b2 = BsP[kk * 65 + tx * 4 + 2], b3 = BsP[kk * 65 + tx * 4 + 3];
        acc[0][0] = fdot2(a0, b0, acc[0][0]); acc[0][1] = fdot2(a0, b1, acc[0][1]);
        acc[0][2] = fdot2(a0, b2, acc[0][2]); acc[0][3] = fdot2(a0, b3, acc[0][3]);
        acc[1][0] = fdot2(a1, b0, acc[1][0]); acc[1][1] = fdot2(a1, b1, acc[1][1]);
        acc[1][2] = fdot2(a1, b2, acc[1][2]); acc[1][3] = fdot2(a1, b3, acc[1][3]);
        acc[2][0] = fdot2(a2, b0, acc[2][0]); acc[2][1] = fdot2(a2, b1, acc[2][1]);
        acc[2][2] = fdot2(a2, b2, acc[2][2]); acc[2][3] = fdot2(a2, b3, acc[2][3]);
        acc[3][0] = fdot2(a3, b0, acc[3][0]); acc[3][1] = fdot2(a3, b1, acc[3][1]);
        acc[3][2] = fdot2(a3, b2, acc[3][2]); acc[3][3] = fdot2(a3, b3, acc[3][3]);
      }
    }
    __syncthreads();
  }
  if (tid < 256) {
    for (int i = 0; i < 4; i++) {
      int gm = bm + ty * 4 + i; if (gm >= M) continue;
      for (int j = 0; j < 4; j++) {
        int gn = bn + tx * 4 + j; if (gn >= N) continue;
        C[(size_t)gm * ldc + gn] = acc[i][j] + (addvec ? addvec[gn] : 0.f);
      }
    }
  }
}

// ---- T GEMM tile (C = A@W^T + bias, W row-stride ldw), 512-stage/256-compute ----
static __device__ void t_tile_fused(const float* __restrict__ A, int lda,
                                    const float* __restrict__ W, int ldw,
                                    const float* __restrict__ bias,
                                    float* __restrict__ C, int ldc,
                                    int M, int N, int K, int bm, int bn,
                                    int tid, uint32_t* AsP, uint32_t* WsP) {
  const int tx = tid & 15, ty = (tid & 255) >> 4;
  float acc[4][4] = {};
  for (int k0 = 0; k0 < K; k0 += 16) {
    {
      int m = tid & 63, kk = tid >> 6;
      int gm = bm + m, gk = k0 + 2 * kk;
      float v0 = 0.f, v1 = 0.f;
      if (gm < M) {
        if (gk < K)     v0 = A[(size_t)gm * lda + gk];
        if (gk + 1 < K) v1 = A[(size_t)gm * lda + gk + 1];
      }
      AsP[kk * 65 + m] = packh2(v0, v1);
      int gn = bn + m;
      float w0 = 0.f, w1 = 0.f;
      if (gn < N) {
        if (gk < K)     w0 = W[(size_t)gn * ldw + gk];
        if (gk + 1 < K) w1 = W[(size_t)gn * ldw + gk + 1];
      }
      WsP[kk * 65 + m] = packh2(w0, w1);
    }
    __syncthreads();
    if (tid < 256) {
#pragma unroll
      for (int kk = 0; kk < 8; kk++) {
        uint32_t a0 = AsP[kk * 65 + ty * 4 + 0], a1 = AsP[kk * 65 + ty * 4 + 1];
        uint32_t a2 = AsP[kk * 65 + ty * 4 + 2], a3 = AsP[kk * 65 + ty * 4 + 3];
        uint32_t b0 = WsP[kk * 65 + tx * 4 + 0], b1 = WsP[kk * 65 + tx * 4 + 1];
        uint32_t b2 = WsP[kk * 65 + tx * 4 + 2], b3 = WsP[kk * 65 + tx * 4 + 3];
        acc[0][0] = fdot2(a0, b0, acc[0][0]); acc[0][1] = fdot2(a0, b1, acc[0][1]);
        acc[0][2] = fdot2(a0, b2, acc[0][2]); acc[0][3] = fdot2(a0, b3, acc[0][3]);
        acc[1][0] = fdot2(a1, b0, acc[1][0]); acc[1][1] = fdot2(a1, b1, acc[1][1]);
        acc[1][2] = fdot2(a1, b2, acc[1][2]); acc[1][3] = fdot2(a1, b3, acc[1][3]);
        acc[2][0] = fdot2(a2, b0, acc[2][0]); acc[2][1] = fdot2(a2, b1, acc[2][1]);
        acc[2][2] = fdot2(a2, b2, acc[2][2]); acc[2][3] = fdot2(a2, b3, acc[2][3]);
        acc[3][0] = fdot2(a3, b0, acc[3][0]); acc[3][1] = fdot2(a3, b1, acc[3][1]);
        acc[3][2] = fdot2(a3, b2, acc[3][2]); acc[3][3] = fdot2(a3, b3, acc[3][3]);
      }
    }
    __syncthreads();
  }
  if (tid < 256) {
    for (int i = 0; i < 4; i++) {
      int gm = bm + ty * 4 + i; if (gm >= M) continue;
      for (int j = 0; j < 4; j++) {
        int gn = bn + tx * 4 + j; if (gn >= N) continue;
        C[(size_t)gm * ldc + gn] = acc[i][j] + bias[gn];
      }
    }
  }
}

// ---------------- fused LSTM + input-GEMMs + attn + uid + te (R16) ----------------
#define WQL 12
#define WBYTES (WQL * 512 * 16)
__launch_bounds__(512)
__global__ void k_lstm(float* __restrict__ A_f, float* __restrict__ A_b,
                       float* __restrict__ A_d,
                       const float* __restrict__ Wih_f, const float* __restrict__ b_f,
                       const float* __restrict__ Wih_b, const float* __restrict__ b_b,
                       const float* __restrict__ Wih_d, const float* __restrict__ b_d,
                       const float* __restrict__ Whh_f, const float* __restrict__ Whh_b,
                       const float* __restrict__ Whh_d,
                       float* __restrict__ hh, float* __restrict__ hdec,
                       float* zpub, uint32_t* hpub, int* flag_z, int* flag_h, int* cnt,
                       const int* __restrict__ loc, const int* __restrict__ tim,
                       const int* __restrict__ cid, const int* __restrict__ target,
                       const float* __restrict__ weight, const float* __restrict__ emb_tim_w,
                       const float* __restrict__ weight_cid,
                       const float* __restrict__ ts, const float* __restrict__ pd,
                       const float* __restrict__ pct,
                       float* __restrict__ S1, float* __restrict__ S2,
                       const int* __restrict__ uid, const float* __restrict__ emb_uid_w,
                       const float* __restrict__ fc_user_w, const float* __restrict__ fc_user_b,
                       float* __restrict__ uid_emb, float* __restrict__ te) {
  const int b = blockIdx.x;
  const int tid = threadIdx.x;
  __shared__ __align__(16) unsigned char smem[WBYTES + 2048 + 4096];
  uint4* wl = (uint4*)smem;
  uint4* hbuf = (uint4*)(smem + WBYTES);
  float* zbuf = (float*)(smem + WBYTES + 2048);

  if (b < 6 && tid < 128) hbuf[tid] = make_uint4(0, 0, 0, 0);

  if (b < 2) {
    float* A = (b == 0) ? A_f : A_b;
    const float* Whh = (b == 0) ? Whh_f : Whh_b;
    int* mycnt = cnt + b * 32;
    const bool act = tid < 500;
    uint4 wv0[10], wv1[10];
    uint32_t wa[128];
    if (act) {
      const float* wr0 = Whh + (size_t)tid * EHID;
      const float* wr1 = Whh + (size_t)(tid + 500) * EHID;
#pragma unroll
      for (int q = 0; q < 6; q++) {
        float t0[8], t1[8];
#pragma unroll
        for (int cc = 0; cc < 8; cc++) {
          int col = 208 + 8 * q + cc;
          t0[cc] = (col < EHID) ? wr0[col] : 0.f;
          t1[cc] = (col < EHID) ? wr1[col] : 0.f;
        }
        wl[(q * 2 + 0) * 512 + tid] = packq(t0);
        wl[(q * 2 + 1) * 512 + tid] = packq(t1);
      }
#pragma unroll
      for (int k = 0; k < 16; k++) {
        uint4 p0 = packq(wr0 + 8 * (10 + k));
        uint4 p1 = packq(wr1 + 8 * (10 + k));
        AW(wa[k * 4 + 0], p0.x); AW(wa[k * 4 + 1], p0.y);
        AW(wa[k * 4 + 2], p0.z); AW(wa[k * 4 + 3], p0.w);
        AW(wa[64 + k * 4 + 0], p1.x); AW(wa[64 + k * 4 + 1], p1.y);
        AW(wa[64 + k * 4 + 2], p1.z); AW(wa[64 + k * 4 + 3], p1.w);
      }
#pragma unroll
      for (int q = 0; q < 10; q++) { wv0[q] = packq(wr0 + 8 * q); wv1[q] = packq(wr1 + 8 * q); }
    }
    if (tid == 0) spin_cnt(&mycnt[0], 16);
    __syncthreads();
    float c = 0.f;
    float aA = act ? A[tid] : 0.f;
    float aB = act ? A[500 + tid] : 0.f;
    __syncthreads();
    for (int t = 0; t < HIST; t++) {
      const uint4* hb = hbuf + (t & 1) * 32;
      int tn = (t + 1 < HIST) ? t + 1 : t;
      if ((tn & 63) == 0 && tn > t) {
        if (tid == 0) spin_cnt(&mycnt[tn >> 6], 16);
        __syncthreads();
      }
      if (act) {
        float z0 = aA, z1 = aB, y0 = 0.f, y1 = 0.f;
        aA = A[tn * 1000 + tid];
        aB = A[tn * 1000 + 500 + tid];
#pragma unroll
        for (int q = 0; q < 10; q++) {
          uint4 hq = hb[q];
          z0 = dotq(wv0[q], hq, z0);
          z1 = dotq(wv1[q], hq, z1);
        }
#pragma unroll
        for (int k = 0; k < 16; k++) {
          uint4 hq = hb[10 + k];
          uint4 u0, u1;
          ARQ(u0, wa, k * 4);
          ARQ(u1, wa, 64 + k * 4);
          y0 = dotq(u0, hq, y0);
          y1 = dotq(u1, hq, y1);
        }
#pragma unroll
        for (int q = 0; q < 6; q++) {
          uint4 hq = hb[26 + q];
          z0 = dotq(wl[(q * 2 + 0) * 512 + tid], hq, z0);
          z1 = dotq(wl[(q * 2 + 1) * 512 + tid], hq, z1);
        }
        zbuf[tid] = z0 + y0;
        zbuf[500 + tid] = z1 + y1;
      }
      __syncthreads();
      float hval = 0.f;
      if (tid < EHID) {
        float zi = zbuf[tid], zf = zbuf[250 + tid], zg = zbuf[500 + tid], zo = zbuf[750 + tid];
        c = sigf(zf) * c + sigf(zi) * tanh_f(zg);
        hval = sigf(zo) * tanh_f(c);
        if (b == 0) hh[(size_t)t * HID + tid] = hval;
        else        hh[(size_t)(HIST - 1 - t) * HID + EHID + tid] = hval;
      }
      float hother = __shfl_xor(hval, 1);
      uint32_t* hw = (uint32_t*)(hbuf + ((t + 1) & 1) * 32);
      if (tid < EHID && !(tid & 1)) hw[tid >> 1] = packh2(hval, hother);
      __syncthreads();
    }
  } else if (b < 6) {
    const int gi = b - 2;
    const int j = tid;
    const bool act = (j < 500);
    int* dcnt = cnt + 64;
    uint4 wv[20];
    uint32_t wa[128];
    if (act) {
      const float* wr = Whh_d + (size_t)(gi * 500 + j) * HID;
#pragma unroll
      for (int q = 0; q < 12; q++) {
        float tmp[8];
#pragma unroll
        for (int cc = 0; cc < 8; cc++) {
          int col = 416 + 8 * q + cc;
          tmp[cc] = (col < HID) ? wr[col] : 0.f;
        }
        wl[q * 512 + tid] = packq(tmp);
      }
#pragma unroll
      for (int k = 0; k < 32; k++) {
        uint4 pq = packq(wr + 8 * (20 + k));
        AW(wa[k * 4 + 0], pq.x); AW(wa[k * 4 + 1], pq.y);
        AW(wa[k * 4 + 2], pq.z); AW(wa[k * 4 + 3], pq.w);
      }
#pragma unroll
      for (int q = 0; q < 20; q++) wv[q] = packq(wr + 8 * q);
    }
    if (tid == 0) spin_cnt(&dcnt[0], 32);
    __syncthreads();
    float c = 0.f;
    float aD = act ? A_d[gi * 500 + j] : 0.f;
    __syncthreads();
    for (int t = 0; t < TGT; t++) {
      const uint4* hb = hbuf + (t & 1) * 64;
      int tn = (t + 1 < TGT) ? t + 1 : t;
      if ((tn & 63) == 0 && tn > t) {
        if (tid == 0) spin_cnt(&dcnt[tn >> 6], 32);
        __syncthreads();
      }
      float z = 0.f;
      if (act) {
        float z0 = aD, z1 = 0.f, z2 = 0.f, z3 = 0.f;
        aD = A_d[tn * 2000 + gi * 500 + j];
#pragma unroll
        for (int q = 0; q < 20; q += 2) {
          z0 = dotq(wv[q], hb[q], z0);
          z1 = dotq(wv[q + 1], hb[q + 1], z1);
        }
#pragma unroll
        for (int k = 0; k < 32; k += 2) {
          uint4 u0, u1;
          ARQ(u0, wa, k * 4);
          ARQ(u1, wa, (k + 1) * 4);
          z2 = dotq(u0, hb[20 + k], z2);
          z3 = dotq(u1, hb[21 + k], z3);
        }
#pragma unroll
        for (int q = 0; q < 12; q += 2) {
          z0 = dotq(wl[q * 512 + tid], hb[52 + q], z0);
          z1 = dotq(wl[(q + 1) * 512 + tid], hb[53 + q], z1);
        }
        z = (z0 + z1) + (z2 + z3);
      }
      if (gi < 3) {
        if (act) zpub[gi * 512 + j] = z;
        __threadfence();
        __syncthreads();
        if (tid == 0) {
          __hip_atomic_store(&flag_z[t * 3 + gi], 1, __ATOMIC_RELEASE, __HIP_MEMORY_SCOPE_AGENT);
          spin_flag(&flag_h[t]);
        }
        __syncthreads();
        uint32_t* hw = (uint32_t*)(hbuf + ((t + 1) & 1) * 64);
        if (tid < 250)
          hw[tid] = __hip_atomic_load(&hpub[tid], __ATOMIC_RELAXED, __HIP_MEMORY_SCOPE_AGENT);
        __syncthreads();
      } else {
        if (tid == 0) {
          spin_flag(&flag_z[t * 3 + 0]);
          spin_flag(&flag_z[t * 3 + 1]);
          spin_flag(&flag_z[t * 3 + 2]);
        }
        __syncthreads();
        float hval = 0.f;
        if (act) {
          float zi = __hip_atomic_load(&zpub[0 * 512 + j], __ATOMIC_RELAXED, __HIP_MEMORY_SCOPE_AGENT);
          float zf = __hip_atomic_load(&zpub[1 * 512 + j], __ATOMIC_RELAXED, __HIP_MEMORY_SCOPE_AGENT);
          float zg = __hip_atomic_load(&zpub[2 * 512 + j], __ATOMIC_RELAXED, __HIP_MEMORY_SCOPE_AGENT);
          c = sigf(zf) * c + sigf(zi) * tanh_f(zg);
          hval = sigf(z) * tanh_f(c);
          hdec[(size_t)t * HID + j] = hval;
        }
        float hother = __shfl_xor(hval, 1);
        uint32_t* hw = (uint32_t*)(hbuf + ((t + 1) & 1) * 64);
        if (act && !(j & 1)) {
          uint32_t p = packh2(hval, hother);
          hw[j >> 1] = p;
          __hip_atomic_store(&hpub[j >> 1], p, __ATOMIC_RELAXED, __HIP_MEMORY_SCOPE_AGENT);
        }
        __threadfence();
        __syncthreads();
        if (tid == 0)
          __hip_atomic_store(&flag_h[t], 1, __ATOMIC_RELEASE, __HIP_MEMORY_SCOPE_AGENT);
      }
    }
  } else if (b == 6) {
    float* u = (float*)smem;
    if (tid < 64) u[tid] = emb_uid_w[(size_t)uid[0] * 64 + tid];
    __syncthreads();
    if (tid < HID) {
      float a = fc_user_b[tid];
      for (int k = 0; k < 64; k++) a += u[k] * fc_user_w[tid * 64 + k];
      uid_emb[tid] = a;
    }
  } else if (b < 903) {
    const int g = b - 7;
    const int chunk = g >> 5, w = g & 31;
    uint32_t* AsP = (uint32_t*)smem;
    uint32_t* WsP = AsP + 8 * 65;
    if (w < 16) {
      gemm_tile_emb(loc, tim, cid, weight, emb_tim_w, weight_cid, 0,
                    Wih_f, b_f, A_f, 1000, HIST, 1000, chunk * 64, w * 64, 0,
                    tid, AsP, WsP);
      __threadfence();
      __syncthreads();
      if (tid == 0)
        __hip_atomic_fetch_add(&cnt[chunk], 1, __ATOMIC_RELEASE, __HIP_MEMORY_SCOPE_AGENT);
    } else {
      gemm_tile_emb(loc, tim, cid, weight, emb_tim_w, weight_cid, 0,
                    Wih_b, b_b, A_b, 1000, HIST, 1000, chunk * 64, (w - 16) * 64, 1,
                    tid, AsP, WsP);
      __threadfence();
      __syncthreads();
      if (tid == 0)
        __hip_atomic_fetch_add(&cnt[32 + chunk], 1, __ATOMIC_RELEASE, __HIP_MEMORY_SCOPE_AGENT);
    }
  } else if (b < 1031) {
    const int g = b - 903;
    const int mt = g >> 5, nt = g & 31;
    uint32_t* AsP = (uint32_t*)smem;
    uint32_t* WsP = AsP + 8 * 65;
    gemm_tile_emb(loc, tim, cid, weight, emb_tim_w, weight_cid, HIST,
                  Wih_d, b_d, A_d, 2000, TGT, 2000, mt * 64, nt * 64, 0,
                  tid, AsP, WsP);
    __threadfence();
    __syncthreads();
    if (tid == 0)
      __hip_atomic_fetch_add(&cnt[64 + mt], 1, __ATOMIC_RELEASE, __HIP_MEMORY_SCOPE_AGENT);
  } else if (b < 1287) {
    const int i = b - 1031;
    float* e = (float*)smem;
    float* red = ((float*)smem) + HIST;
    const int loc_i = loc[HIST + i], tim_i = tim[HIST + i];
    for (int tab = 0; tab < 3; tab++) {
      for (int jj = tid; jj < HIST; jj += 512) {
        float v;
        if (tab == 0)      v = 1.f / pd[(size_t)loc_i * 10000 + loc[jj]];
        else if (tab == 1) v = ts[tim_i * 48 + tim[jj]];
        else               v = pct[tim_i * 300 + cid[jj]];
        e[jj] = v;
      }
      __syncthreads();
      float mx = -1e30f;
      for (int jj = tid; jj < HIST; jj += 512) mx = fmaxf(mx, e[jj]);
      red[tid] = mx; __syncthreads();
      for (int s = 256; s > 0; s >>= 1) { if (tid < s) red[tid] = fmaxf(red[tid], red[tid + s]); __syncthreads(); }
      mx = red[0]; __syncthreads();
      float sm = 0.f;
      for (int jj = tid; jj < HIST; jj += 512) sm += __expf(e[jj] - mx);
      red[tid] = sm; __syncthreads();
      for (int s = 256; s > 0; s >>= 1) { if (tid < s) red[tid] += red[tid + s]; __syncthreads(); }
      float inv = 1.f / red[0]; __syncthreads();
      for (int jj = tid; jj < HIST; jj += 512) {
        float p = __expf(e[jj] - mx) * inv;
        if (tab == 0) S1[(size_t)i * HIST + jj] = p; else S1[(size_t)i * HIST + jj] += p;
      }
      __syncthreads();
    }
    int lj = 0, tj = 0, cj = 0;
    if (tid < TGT) { lj = loc[HIST + tid]; tj = tim[HIST + tid]; cj = cid[HIST + tid]; }
    for (int tab = 0; tab < 3; tab++) {
      float v = 0.f;
      if (tid < TGT) {
        if (tab == 0)      v = 1.f / pd[(size_t)loc_i * 10000 + lj];
        else if (tab == 1) v = ts[tim_i * 48 + tj];
        else               v = pct[tim_i * 300 + cj];
        if (tid > i) v = 0.f;
        red[tid] = v;
      }
      __syncthreads();
      for (int s = 128; s > 0; s >>= 1) { if (tid < s) red[tid] = fmaxf(red[tid], red[tid + s]); __syncthreads(); }
      float mx = red[0]; __syncthreads();
      float ex = (tid < TGT) ? __expf(v - mx) : 0.f;
      if (tid < TGT) red[tid] = ex;
      __syncthreads();
      for (int s = 128; s > 0; s >>= 1) { if (tid < s) red[tid] += red[tid + s]; __syncthreads(); }
      float p = ex / red[0]; __syncthreads();
      if (tid < TGT) {
        if (tab == 0) S2[(size_t)i * TGT + tid] = p; else S2[(size_t)i * TGT + tid] += p;
      }
      __syncthreads();
    }
  } else {
    const int r0 = (b - 1287) * 16;
    for (int idx = tid; idx < 16 * 256; idx += 512) {
      int row = r0 + (idx >> 8), col = idx & 255;
      te[(size_t)row * 256 + col] = weight[(size_t)target[row] * 256 + col];
    }
  }
}

// ---------------- single fused tail (everything after the LSTM) ----------------
// Grid = 1002 blocks x 512 threads; ALL spins wait on lower block-IDs only
// (forward progress by in-order scheduling + producer retirement).
//   b0        : user attn -> cu, cu_flag
//   b1..21    : cubias (spin cu_flag) -> fb/fb2, incr fbcnt
//   b22..53   : nn S2@hdec -> outb[:, :500], incr scnt[mt]   (8 nt x 4 mt)
//   b54..85   : nn S1@hh   -> outb[:, 500:], incr scnt[mt]
//   b86..713  : fc_final tiles (157 nt x 4 mt; spin scnt[mt]==16, fbcnt==21)
//               -> score, incr rcnt[mt]
//   b714..745 : y1 tiles (8 nt x 4 mt; same spins) -> y1
//   b746..1001: log-softmax row r=b-746 (spin rcnt[r>>6]==157)
__launch_bounds__(512)
__global__ void k_tail(const float* __restrict__ uid_emb, const float* __restrict__ hh,
                       float* __restrict__ cu, int* cu_flag, int* fbcnt,
                       int* scnt, int* rcnt,
                       const float* __restrict__ Wf, const float* __restrict__ bf,
                       const float* __restrict__ W2, const float* __restrict__ b2,
                       float* __restrict__ fb, float* __restrict__ fb2,
                       const float* __restrict__ S2, const float* __restrict__ hdec,
                       const float* __restrict__ S1, float* __restrict__ outb,
                       float* __restrict__ score, float* __restrict__ y1) {
  const int b = blockIdx.x;
  const int tid = threadIdx.x;
  __shared__ __align__(16) float sh[HIST + 512];
  if (b == 0) {
    float* s = sh;
    float* red = sh + HIST;
    __shared__ __align__(16) float ue[HID];
    if (tid < HID) ue[tid] = uid_emb[tid];
    __syncthreads();
    for (int t = tid; t < HIST; t += 512) {
      const float4* hr = (const float4*)(hh + (size_t)t * HID);
      const float4* uv = (const float4*)ue;
      float a = 0.f;
#pragma unroll 5
      for (int k = 0; k < 125; k++) {
        float4 h4 = hr[k], u4 = uv[k];
        a += h4.x * u4.x + h4.y * u4.y + h4.z * u4.z + h4.w * u4.w;
      }
      s[t] = a;
    }
    __syncthreads();
    float mx = -1e30f;
    for (int t = tid; t < HIST; t += 512) mx = fmaxf(mx, s[t]);
    red[tid] = mx; __syncthreads();
    for (int st = 256; st > 0; st >>= 1) { if (tid < st) red[tid] = fmaxf(red[tid], red[tid + st]); __syncthreads(); }
    mx = red[0]; __syncthreads();
    float sm = 0.f;
    for (int t = tid; t < HIST; t += 512) sm += __expf(s[t] - mx);
    red[tid] = sm; __syncthreads();
    for (int st = 256; st > 0; st >>= 1) { if (tid < st) red[tid] += red[tid + st]; __syncthreads(); }
    float inv = 1.f / red[0]; __syncthreads();
    for (int t = tid; t < HIST; t += 512) s[t] = __expf(s[t] - mx) * inv;
    __syncthreads();
    if (tid < HID) {
      float a0 = 0.f, a1 = 0.f, a2 = 0.f, a3 = 0.f;
      for (int t = 0; t < HIST; t += 4) {
        a0 += s[t]     * hh[(size_t)t * HID + tid];
        a1 += s[t + 1] * hh[(size_t)(t + 1) * HID + tid];
        a2 += s[t + 2] * hh[(size_t)(t + 2) * HID + tid];
        a3 += s[t + 3] * hh[(size_t)(t + 3) * HID + tid];
      }
      cu[tid] = (a0 + a1) + (a2 + a3);
    }
    __threadfence();
    __syncthreads();
    if (tid == 0)
      __hip_atomic_store(cu_flag, 1, __ATOMIC_RELEASE, __HIP_MEMORY_SCOPE_AGENT);
  } else if (b < 22) {
    float* cus = sh;
    if (tid == 0) spin_flag(cu_flag);
    __syncthreads();
    if (tid < 500) cus[tid] = __hip_atomic_load(&cu[tid], __ATOMIC_RELAXED, __HIP_MEMORY_SCOPE_AGENT);
    __syncthreads();
    int n = (b - 1) * 512 + tid;
    const float4* cv = (const float4*)cus;
    if (n < 10000) {
      const float4* w = (const float4*)(Wf + (size_t)n * 1500 + 1000);
      float a = bf[n];
#pragma unroll 5
      for (int k = 0; k < 125; k++) {
        float4 wv = w[k], uv = cv[k];
        a += wv.x * uv.x + wv.y * uv.y + wv.z * uv.z + wv.w * uv.w;
      }
      fb[n] = a;
    } else if (n < 10500) {
      int m = n - 10000;
      const float4* w = (const float4*)(W2 + (size_t)m * 1500 + 1000);
      float a = b2[m];
#pragma unroll 5
      for (int k = 0; k < 125; k++) {
        float4 wv = w[k], uv = cv[k];
        a += wv.x * uv.x + wv.y * uv.y + wv.z * uv.z + wv.w * uv.w;
      }
      fb2[m] = a;
    }
    __threadfence();
    __syncthreads();
    if (tid == 0)
      __hip_atomic_fetch_add(fbcnt, 1, __ATOMIC_RELEASE, __HIP_MEMORY_SCOPE_AGENT);
  } else if (b < 54) {
    const int g = b - 22;
    const int nt = g & 7, mt = g >> 3;
    uint32_t* AsP = (uint32_t*)sh;
    uint32_t* BsP = AsP + 8 * 65;
    nn_tile_fused(S2, TGT, hdec, HID, uid_emb, outb, 1000,
                  TGT, HID, TGT, mt * 64, nt * 64, tid, AsP, BsP);
    __threadfence();
    __syncthreads();
    if (tid == 0)
      __hip_atomic_fetch_add(&scnt[mt], 1, __ATOMIC_RELEASE, __HIP_MEMORY_SCOPE_AGENT);
  } else if (b < 86) {
    const int g = b - 54;
    const int nt = g & 7, mt = g >> 3;
    uint32_t* AsP = (uint32_t*)sh;
    uint32_t* BsP = AsP + 8 * 65;
    nn_tile_fused(S1, HIST, hh, HID, nullptr, outb + 500, 1000,
                  TGT, HID, HIST, mt * 64, nt * 64, tid, AsP, BsP);
    __threadfence();
    __syncthreads();
    if (tid == 0)
      __hip_atomic_fetch_add(&scnt[mt], 1, __ATOMIC_RELEASE, __HIP_MEMORY_SCOPE_AGENT);
  } else if (b < 714) {
    const int g = b - 86;
    const int nt = g % 157, mt = g / 157;
    if (tid == 0) { spin_cnt(fbcnt, 21); spin_cnt(&scnt[mt], 16); }
    __syncthreads();
    uint32_t* AsP = (uint32_t*)sh;
    uint32_t* WsP = AsP + 8 * 65;
    t_tile_fused(outb, 1000, Wf, 1500, fb, score, 10000,
                 TGT, 10000, 1000, mt * 64, nt * 64, tid, AsP, WsP);
    __threadfence();
    __syncthreads();
    if (tid == 0)
      __hip_atomic_fetch_add(&rcnt[mt], 1, __ATOMIC_RELEASE, __HIP_MEMORY_SCOPE_AGENT);
  } else if (b < 746) {
    const int g = b - 714;
    const int nt = g & 7, mt = g >> 3;
    if (tid == 0) { spin_cnt(fbcnt, 21); spin_cnt(&scnt[mt], 16); }
    __syncthreads();
    uint32_t* AsP = (uint32_t*)sh;
    uint32_t* WsP = AsP + 8 * 65;
    t_tile_fused(outb, 1000, W2, 1500, fb2, y1, 500,
                 TGT, 500, 1000, mt * 64, nt * 64, tid, AsP, WsP);
  } else {
    const int r = b - 746;
    if (tid == 0) spin_cnt(&rcnt[r >> 6], 157);
    __syncthreads();
    float* red = sh;
    float* row = score + (size_t)r * 10000;
    float mx = -1e30f;
    for (int j = tid; j < 10000; j += 512) mx = fmaxf(mx, row[j]);
    red[tid] = mx; __syncthreads();
    for (int s = 256; s > 0; s >>= 1) { if (tid < s) red[tid] = fmaxf(red[tid], red[tid + s]); __syncthreads(); }
    mx = red[0]; __syncthreads();
    float sm = 0.f;
    for (int j = tid; j < 10000; j += 512) sm += __expf(row[j] - mx);
    red[tid] = sm; __syncthreads();
    for (int s = 256; s > 0; s >>= 1) { if (tid < s) red[tid] += red[tid + s]; __syncthreads(); }
    float lse = mx + __logf(red[0]);
    __syncthreads();
    for (int j = tid; j < 10000; j += 512) row[j] = row[j] - lse;
  }
}

extern "C" void kernel_launch(void* const* d_in, const int* in_sizes, int n_in,
                              void* d_out, int out_size, void* d_ws, size_t ws_size,
                              hipStream_t stream) {
  (void)in_sizes; (void)n_in; (void)out_size; (void)ws_size;
  const int* loc = (const int*)d_in[0];
  const int* tim = (const int*)d_in[1];
  const int* cid = (const int*)d_in[2];
  const int* uid = (const int*)d_in[3];
  const int* target = (const int*)d_in[4];
  const float* ts = (const float*)d_in[6];
  const float* pd = (const float*)d_in[7];
  const float* pct = (const float*)d_in[8];
  const float* weight = (const float*)d_in[9];
  const float* weight_cid = (const float*)d_in[10];
  const float* emb_uid_w = (const float*)d_in[11];
  const float* emb_tim_w = (const float*)d_in[12];
  const float* enc_Wih_f = (const float*)d_in[13];
  const float* enc_Whh_f = (const float*)d_in[14];
  const float* enc_b_f = (const float*)d_in[15];
  const float* enc_Wih_b = (const float*)d_in[16];
  const float* enc_Whh_b = (const float*)d_in[17];
  const float* enc_b_b = (const float*)d_in[18];
  const float* dec_Wih = (const float*)d_in[19];
  const float* dec_Whh = (const float*)d_in[20];
  const float* dec_b = (const float*)d_in[21];
  const float* fc_user_w = (const float*)d_in[22];
  const float* fc_user_b = (const float*)d_in[23];
  const float* fc_final_w = (const float*)d_in[24];
  const float* fc_final_b = (const float*)d_in[25];
  const float* fc_final2_w = (const float*)d_in[26];
  const float* fc_final2_b = (const float*)d_in[27];

  float* score = (float*)d_out;                  // 256*10000
  float* y1 = score + (size_t)TGT * 10000;       // 256*500
  float* te = y1 + (size_t)TGT * HID;            // 256*256

  float* ws = (float*)d_ws;
  float* A_f = ws;                                // HIST*1000
  float* A_b = A_f + (size_t)HIST * 1000;         // HIST*1000
  float* A_d = A_b + (size_t)HIST * 1000;         // TGT*2000
  float* hh = A_d + (size_t)TGT * 2000;           // HIST*500
  float* hdec = hh + (size_t)HIST * HID;          // TGT*500
  float* S1 = hdec + (size_t)TGT * HID;           // TGT*HIST
  float* S2 = S1 + (size_t)TGT * HIST;            // TGT*TGT
  float* outb = S2 + (size_t)TGT * TGT;           // TGT*1000
  float* cu = outb + (size_t)TGT * 1000;          // 512
  float* fb = cu + 512;                           // 10016
  float* fb2 = fb + 10016;                        // 512
  float* uid_emb = fb2 + 512;                     // 512
  float* zpub = uid_emb + 512;                    // 3*512
  uint32_t* hpub = (uint32_t*)(zpub + 3 * 512);   // 256
  int* flag_z = (int*)(hpub + 256);               // 3*256
  int* flag_h = flag_z + 3 * TGT;                 // 256
  int* cnt = flag_h + TGT;                        // 96
  int* cu_flag = cnt + 96;                        // 1
  int* fbcnt = cu_flag + 1;                       // 1
  int* scnt = fbcnt + 1;                          // 4
  int* rcnt = scnt + 4;                           // 4
  const int n_flags = 4 * TGT + 96 + 10;

  hipMemsetAsync(flag_z, 0, n_flags * sizeof(int), stream);

  k_lstm<<<dim3(1303), dim3(512), 0, stream>>>(A_f, A_b, A_d,
                                               enc_Wih_f, enc_b_f, enc_Wih_b, enc_b_b,
                                               dec_Wih, dec_b,
                                               enc_Whh_f, enc_Whh_b, dec_Whh,
                                               hh, hdec, zpub, hpub, flag_z, flag_h, cnt,
                                               loc, tim, cid, target,
                                               weight, emb_tim_w, weight_cid,
                                               ts, pd, pct, S1, S2,
                                               uid, emb_uid_w, fc_user_w, fc_user_b,
                                               uid_emb, te);

  k_tail<<<dim3(1002), dim3(512), 0, stream>>>(uid_emb, hh, cu, cu_flag, fbcnt, scnt, rcnt,
                                               fc_final_w, fc_final_b,
                                               fc_final2_w, fc_final2_b, fb, fb2,
                                               S2, hdec, S1, outb, score, y1);
}

// Round 18
// 4468.431 us; speedup vs baseline: 1.3615x; 1.3615x over previous
//
#include <hip/hip_runtime.h>
#include <stdint.h>

#define HIST 1792
#define TGT 256
#define SEQ 2048
#define INPUT 352
#define EHID 250
#define HID 500

typedef _Float16 h2_t __attribute__((ext_vector_type(2)));

static __device__ __forceinline__ float fdot2(uint32_t a, uint32_t b, float c) {
  return __builtin_amdgcn_fdot2(__builtin_bit_cast(h2_t, a),
                                __builtin_bit_cast(h2_t, b), c, false);
}
static __device__ __forceinline__ uint32_t packh2(float lo, float hi) {
  h2_t h; h[0] = (_Float16)lo; h[1] = (_Float16)hi;
  return __builtin_bit_cast(uint32_t, h);
}
static __device__ __forceinline__ uint4 packq(const float* p) {
  uint4 r;
  r.x = packh2(p[0], p[1]); r.y = packh2(p[2], p[3]);
  r.z = packh2(p[4], p[5]); r.w = packh2(p[6], p[7]);
  return r;
}
static __device__ __forceinline__ float dotq(uint4 w, uint4 h, float acc) {
  acc = fdot2(w.x, h.x, acc); acc = fdot2(w.y, h.y, acc);
  acc = fdot2(w.z, h.z, acc); acc = fdot2(w.w, h.w, acc);
  return acc;
}
static __device__ __forceinline__ float sigf(float x) {
  x = fminf(fmaxf(x, -30.f), 30.f);
  return 1.f / (1.f + __expf(-x));
}
static __device__ __forceinline__ float tanh_f(float x) {
  x = fminf(fmaxf(x, -15.f), 15.f);
  float e = __expf(2.f * x);
  return (e - 1.f) / (e + 1.f);
}
static __device__ __forceinline__ void spin_flag(volatile int* f) {
  while (__hip_atomic_load(f, __ATOMIC_ACQUIRE, __HIP_MEMORY_SCOPE_AGENT) == 0)
    __builtin_amdgcn_s_sleep(2);
}
static __device__ __forceinline__ void spin_cnt(volatile int* f, int target) {
  while (__hip_atomic_load(f, __ATOMIC_ACQUIRE, __HIP_MEMORY_SCOPE_AGENT) < target)
    __builtin_amdgcn_s_sleep(2);
}
#define AW(dst, src) asm("v_accvgpr_write_b32 %0, %1" : "=a"(dst) : "v"(src))
#define AR(dst, src) asm("v_accvgpr_read_b32 %0, %1" : "=v"(dst) : "a"(src))
#define ARQ(dst, arr, base) do { AR(dst.x, arr[(base)+0]); AR(dst.y, arr[(base)+1]); AR(dst.z, arr[(base)+2]); AR(dst.w, arr[(base)+3]); } while(0)

// ---- in-fused input GEMM tile: A = embeddings gathered on the fly ----
static __device__ void gemm_tile_emb(const int* __restrict__ loc, const int* __restrict__ tim,
                                     const int* __restrict__ cid,
                                     const float* __restrict__ weight,
                                     const float* __restrict__ emb_tim_w,
                                     const float* __restrict__ weight_cid,
                                     int rowoff,
                                     const float* __restrict__ W,
                                     const float* __restrict__ bias,
                                     float* __restrict__ C, int ldc,
                                     int M, int N, int bm, int bn, int revA,
                                     int tid, uint32_t* AsP, uint32_t* WsP) {
  const int tx = tid & 15, ty = (tid & 255) >> 4;
  float acc[4][4] = {};
  for (int k0 = 0; k0 < INPUT; k0 += 16) {
    {
      int m = tid & 63, kk = tid >> 6;
      int gm = bm + m, gk = k0 + 2 * kk;
      float v0 = 0.f, v1 = 0.f;
      if (gm < M) {
        int am = (revA ? (M - 1 - gm) : gm) + rowoff;
        if (gk < 256) {
          const float* wp = weight + (size_t)loc[am] * 256 + gk;
          v0 = wp[0]; v1 = wp[1];
        } else if (gk < 288) {
          const float* wp = emb_tim_w + tim[am] * 32 + (gk - 256);
          v0 = wp[0]; v1 = wp[1];
        } else {
          const float* wp = weight_cid + cid[am] * 64 + (gk - 288);
          v0 = wp[0]; v1 = wp[1];
        }
      }
      AsP[kk * 65 + m] = packh2(v0, v1);
      int gn = bn + m;
      float w0 = 0.f, w1 = 0.f;
      if (gn < N) {
        const float* wp = W + (size_t)gn * INPUT + gk;
        w0 = wp[0]; w1 = wp[1];
      }
      WsP[kk * 65 + m] = packh2(w0, w1);
    }
    __syncthreads();
    if (tid < 256) {
#pragma unroll
      for (int kk = 0; kk < 8; kk++) {
        uint32_t a0 = AsP[kk * 65 + ty * 4 + 0], a1 = AsP[kk * 65 + ty * 4 + 1];
        uint32_t a2 = AsP[kk * 65 + ty * 4 + 2], a3 = AsP[kk * 65 + ty * 4 + 3];
        uint32_t b0 = WsP[kk * 65 + tx * 4 + 0], b1 = WsP[kk * 65 + tx * 4 + 1];
        uint32_t b2 = WsP[kk * 65 + tx * 4 + 2], b3 = WsP[kk * 65 + tx * 4 + 3];
        acc[0][0] = fdot2(a0, b0, acc[0][0]); acc[0][1] = fdot2(a0, b1, acc[0][1]);
        acc[0][2] = fdot2(a0, b2, acc[0][2]); acc[0][3] = fdot2(a0, b3, acc[0][3]);
        acc[1][0] = fdot2(a1, b0, acc[1][0]); acc[1][1] = fdot2(a1, b1, acc[1][1]);
        acc[1][2] = fdot2(a1, b2, acc[1][2]); acc[1][3] = fdot2(a1, b3, acc[1][3]);
        acc[2][0] = fdot2(a2, b0, acc[2][0]); acc[2][1] = fdot2(a2, b1, acc[2][1]);
        acc[2][2] = fdot2(a2, b2, acc[2][2]); acc[2][3] = fdot2(a2, b3, acc[2][3]);
        acc[3][0] = fdot2(a3, b0, acc[3][0]); acc[3][1] = fdot2(a3, b1, acc[3][1]);
        acc[3][2] = fdot2(a3, b2, acc[3][2]); acc[3][3] = fdot2(a3, b3, acc[3][3]);
      }
    }
    __syncthreads();
  }
  if (tid < 256) {
    for (int i = 0; i < 4; i++) {
      int gm = bm + ty * 4 + i; if (gm >= M) continue;
      for (int j = 0; j < 4; j++) {
        int gn = bn + tx * 4 + j; if (gn >= N) continue;
        C[(size_t)gm * ldc + gn] = acc[i][j] + bias[gn];
      }
    }
  }
}

// ---- NN GEMM tile (C = A@B + addvec), 512-stage/256-compute ----
static __device__ void nn_tile_fused(const float* __restrict__ A, int lda,
                                     const float* __restrict__ B, int ldb,
                                     const float* __restrict__ addvec,
                                     float* __restrict__ C, int ldc,
                                     int M, int N, int K, int bm, int bn,
                                     int tid, uint32_t* AsP, uint32_t* BsP) {
  const int tx = tid & 15, ty = (tid & 255) >> 4;
  float acc[4][4] = {};
  for (int k0 = 0; k0 < K; k0 += 16) {
    {
      int m = tid & 63, kk = tid >> 6;
      int gm = bm + m, gk = k0 + 2 * kk;
      float v0 = 0.f, v1 = 0.f;
      if (gm < M) {
        if (gk < K)     v0 = A[(size_t)gm * lda + gk];
        if (gk + 1 < K) v1 = A[(size_t)gm * lda + gk + 1];
      }
      AsP[kk * 65 + m] = packh2(v0, v1);
      int gn = bn + m;
      float w0 = 0.f, w1 = 0.f;
      if (gn < N) {
        if (gk < K)     w0 = B[(size_t)gk * ldb + gn];
        if (gk + 1 < K) w1 = B[(size_t)(gk + 1) * ldb + gn];
      }
      BsP[kk * 65 + m] = packh2(w0, w1);
    }
    __syncthreads();
    if (tid < 256) {
#pragma unroll
      for (int kk = 0; kk < 8; kk++) {
        uint32_t a0 = AsP[kk * 65 + ty * 4 + 0], a1 = AsP[kk * 65 + ty * 4 + 1];
        uint32_t a2 = AsP[kk * 65 + ty * 4 + 2], a3 = AsP[kk * 65 + ty * 4 + 3];
        uint32_t b0 = BsP[kk * 65 + tx * 4 + 0], b1 = BsP[kk * 65 + tx * 4 + 1];
        uint32_t b2 = BsP[kk * 65 + tx * 4 + 2], b3 = BsP[kk * 65 + tx * 4 + 3];
        acc[0][0] = fdot2(a0, b0, acc[0][0]); acc[0][1] = fdot2(a0, b1, acc[0][1]);
        acc[0][2] = fdot2(a0, b2, acc[0][2]); acc[0][3] = fdot2(a0, b3, acc[0][3]);
        acc[1][0] = fdot2(a1, b0, acc[1][0]); acc[1][1] = fdot2(a1, b1, acc[1][1]);
        acc[1][2] = fdot2(a1, b2, acc[1][2]); acc[1][3] = fdot2(a1, b3, acc[1][3]);
        acc[2][0] = fdot2(a2, b0, acc[2][0]); acc[2][1] = fdot2(a2, b1, acc[2][1]);
        acc[2][2] = fdot2(a2, b2, acc[2][2]); acc[2][3] = fdot2(a2, b3, acc[2][3]);
        acc[3][0] = fdot2(a3, b0, acc[3][0]); acc[3][1] = fdot2(a3, b1, acc[3][1]);
        acc[3][2] = fdot2(a3, b2, acc[3][2]); acc[3][3] = fdot2(a3, b3, acc[3][3]);
      }
    }
    __syncthreads();
  }
  if (tid < 256) {
    for (int i = 0; i < 4; i++) {
      int gm = bm + ty * 4 + i; if (gm >= M) continue;
      for (int j = 0; j < 4; j++) {
        int gn = bn + tx * 4 + j; if (gn >= N) continue;
        C[(size_t)gm * ldc + gn] = acc[i][j] + (addvec ? addvec[gn] : 0.f);
      }
    }
  }
}

// ---------------- fused LSTM + input-GEMMs + attn + uid + te (R16) ----------------
#define WQL 12
#define WBYTES (WQL * 512 * 16)
__launch_bounds__(512)
__global__ void k_lstm(float* __restrict__ A_f, float* __restrict__ A_b,
                       float* __restrict__ A_d,
                       const float* __restrict__ Wih_f, const float* __restrict__ b_f,
                       const float* __restrict__ Wih_b, const float* __restrict__ b_b,
                       const float* __restrict__ Wih_d, const float* __restrict__ b_d,
                       const float* __restrict__ Whh_f, const float* __restrict__ Whh_b,
                       const float* __restrict__ Whh_d,
                       float* __restrict__ hh, float* __restrict__ hdec,
                       float* zpub, uint32_t* hpub, int* flag_z, int* flag_h, int* cnt,
                       const int* __restrict__ loc, const int* __restrict__ tim,
                       const int* __restrict__ cid, const int* __restrict__ target,
                       const float* __restrict__ weight, const float* __restrict__ emb_tim_w,
                       const float* __restrict__ weight_cid,
                       const float* __restrict__ ts, const float* __restrict__ pd,
                       const float* __restrict__ pct,
                       float* __restrict__ S1, float* __restrict__ S2,
                       const int* __restrict__ uid, const float* __restrict__ emb_uid_w,
                       const float* __restrict__ fc_user_w, const float* __restrict__ fc_user_b,
                       float* __restrict__ uid_emb, float* __restrict__ te) {
  const int b = blockIdx.x;
  const int tid = threadIdx.x;
  __shared__ __align__(16) unsigned char smem[WBYTES + 2048 + 4096];
  uint4* wl = (uint4*)smem;
  uint4* hbuf = (uint4*)(smem + WBYTES);
  float* zbuf = (float*)(smem + WBYTES + 2048);

  if (b < 6 && tid < 128) hbuf[tid] = make_uint4(0, 0, 0, 0);

  if (b < 2) {
    float* A = (b == 0) ? A_f : A_b;
    const float* Whh = (b == 0) ? Whh_f : Whh_b;
    int* mycnt = cnt + b * 32;
    const bool act = tid < 500;
    uint4 wv0[10], wv1[10];
    uint32_t wa[128];
    if (act) {
      const float* wr0 = Whh + (size_t)tid * EHID;
      const float* wr1 = Whh + (size_t)(tid + 500) * EHID;
#pragma unroll
      for (int q = 0; q < 6; q++) {
        float t0[8], t1[8];
#pragma unroll
        for (int cc = 0; cc < 8; cc++) {
          int col = 208 + 8 * q + cc;
          t0[cc] = (col < EHID) ? wr0[col] : 0.f;
          t1[cc] = (col < EHID) ? wr1[col] : 0.f;
        }
        wl[(q * 2 + 0) * 512 + tid] = packq(t0);
        wl[(q * 2 + 1) * 512 + tid] = packq(t1);
      }
#pragma unroll
      for (int k = 0; k < 16; k++) {
        uint4 p0 = packq(wr0 + 8 * (10 + k));
        uint4 p1 = packq(wr1 + 8 * (10 + k));
        AW(wa[k * 4 + 0], p0.x); AW(wa[k * 4 + 1], p0.y);
        AW(wa[k * 4 + 2], p0.z); AW(wa[k * 4 + 3], p0.w);
        AW(wa[64 + k * 4 + 0], p1.x); AW(wa[64 + k * 4 + 1], p1.y);
        AW(wa[64 + k * 4 + 2], p1.z); AW(wa[64 + k * 4 + 3], p1.w);
      }
#pragma unroll
      for (int q = 0; q < 10; q++) { wv0[q] = packq(wr0 + 8 * q); wv1[q] = packq(wr1 + 8 * q); }
    }
    if (tid == 0) spin_cnt(&mycnt[0], 16);
    __syncthreads();
    float c = 0.f;
    float aA = act ? A[tid] : 0.f;
    float aB = act ? A[500 + tid] : 0.f;
    __syncthreads();
    for (int t = 0; t < HIST; t++) {
      const uint4* hb = hbuf + (t & 1) * 32;
      int tn = (t + 1 < HIST) ? t + 1 : t;
      if ((tn & 63) == 0 && tn > t) {
        if (tid == 0) spin_cnt(&mycnt[tn >> 6], 16);
        __syncthreads();
      }
      if (act) {
        float z0 = aA, z1 = aB, y0 = 0.f, y1 = 0.f;
        aA = A[tn * 1000 + tid];
        aB = A[tn * 1000 + 500 + tid];
#pragma unroll
        for (int q = 0; q < 10; q++) {
          uint4 hq = hb[q];
          z0 = dotq(wv0[q], hq, z0);
          z1 = dotq(wv1[q], hq, z1);
        }
#pragma unroll
        for (int k = 0; k < 16; k++) {
          uint4 hq = hb[10 + k];
          uint4 u0, u1;
          ARQ(u0, wa, k * 4);
          ARQ(u1, wa, 64 + k * 4);
          y0 = dotq(u0, hq, y0);
          y1 = dotq(u1, hq, y1);
        }
#pragma unroll
        for (int q = 0; q < 6; q++) {
          uint4 hq = hb[26 + q];
          z0 = dotq(wl[(q * 2 + 0) * 512 + tid], hq, z0);
          z1 = dotq(wl[(q * 2 + 1) * 512 + tid], hq, z1);
        }
        zbuf[tid] = z0 + y0;
        zbuf[500 + tid] = z1 + y1;
      }
      __syncthreads();
      float hval = 0.f;
      if (tid < EHID) {
        float zi = zbuf[tid], zf = zbuf[250 + tid], zg = zbuf[500 + tid], zo = zbuf[750 + tid];
        c = sigf(zf) * c + sigf(zi) * tanh_f(zg);
        hval = sigf(zo) * tanh_f(c);
        if (b == 0) hh[(size_t)t * HID + tid] = hval;
        else        hh[(size_t)(HIST - 1 - t) * HID + EHID + tid] = hval;
      }
      float hother = __shfl_xor(hval, 1);
      uint32_t* hw = (uint32_t*)(hbuf + ((t + 1) & 1) * 32);
      if (tid < EHID && !(tid & 1)) hw[tid >> 1] = packh2(hval, hother);
      __syncthreads();
    }
  } else if (b < 6) {
    const int gi = b - 2;
    const int j = tid;
    const bool act = (j < 500);
    int* dcnt = cnt + 64;
    uint4 wv[20];
    uint32_t wa[128];
    if (act) {
      const float* wr = Whh_d + (size_t)(gi * 500 + j) * HID;
#pragma unroll
      for (int q = 0; q < 12; q++) {
        float tmp[8];
#pragma unroll
        for (int cc = 0; cc < 8; cc++) {
          int col = 416 + 8 * q + cc;
          tmp[cc] = (col < HID) ? wr[col] : 0.f;
        }
        wl[q * 512 + tid] = packq(tmp);
      }
#pragma unroll
      for (int k = 0; k < 32; k++) {
        uint4 pq = packq(wr + 8 * (20 + k));
        AW(wa[k * 4 + 0], pq.x); AW(wa[k * 4 + 1], pq.y);
        AW(wa[k * 4 + 2], pq.z); AW(wa[k * 4 + 3], pq.w);
      }
#pragma unroll
      for (int q = 0; q < 20; q++) wv[q] = packq(wr + 8 * q);
    }
    if (tid == 0) spin_cnt(&dcnt[0], 32);
    __syncthreads();
    float c = 0.f;
    float aD = act ? A_d[gi * 500 + j] : 0.f;
    __syncthreads();
    for (int t = 0; t < TGT; t++) {
      const uint4* hb = hbuf + (t & 1) * 64;
      int tn = (t + 1 < TGT) ? t + 1 : t;
      if ((tn & 63) == 0 && tn > t) {
        if (tid == 0) spin_cnt(&dcnt[tn >> 6], 32);
        __syncthreads();
      }
      float z = 0.f;
      if (act) {
        float z0 = aD, z1 = 0.f, z2 = 0.f, z3 = 0.f;
        aD = A_d[tn * 2000 + gi * 500 + j];
#pragma unroll
        for (int q = 0; q < 20; q += 2) {
          z0 = dotq(wv[q], hb[q], z0);
          z1 = dotq(wv[q + 1], hb[q + 1], z1);
        }
#pragma unroll
        for (int k = 0; k < 32; k += 2) {
          uint4 u0, u1;
          ARQ(u0, wa, k * 4);
          ARQ(u1, wa, (k + 1) * 4);
          z2 = dotq(u0, hb[20 + k], z2);
          z3 = dotq(u1, hb[21 + k], z3);
        }
#pragma unroll
        for (int q = 0; q < 12; q += 2) {
          z0 = dotq(wl[q * 512 + tid], hb[52 + q], z0);
          z1 = dotq(wl[(q + 1) * 512 + tid], hb[53 + q], z1);
        }
        z = (z0 + z1) + (z2 + z3);
      }
      if (gi < 3) {
        if (act) zpub[gi * 512 + j] = z;
        __threadfence();
        __syncthreads();
        if (tid == 0) {
          __hip_atomic_store(&flag_z[t * 3 + gi], 1, __ATOMIC_RELEASE, __HIP_MEMORY_SCOPE_AGENT);
          spin_flag(&flag_h[t]);
        }
        __syncthreads();
        uint32_t* hw = (uint32_t*)(hbuf + ((t + 1) & 1) * 64);
        if (tid < 250)
          hw[tid] = __hip_atomic_load(&hpub[tid], __ATOMIC_RELAXED, __HIP_MEMORY_SCOPE_AGENT);
        __syncthreads();
      } else {
        if (tid == 0) {
          spin_flag(&flag_z[t * 3 + 0]);
          spin_flag(&flag_z[t * 3 + 1]);
          spin_flag(&flag_z[t * 3 + 2]);
        }
        __syncthreads();
        float hval = 0.f;
        if (act) {
          float zi = __hip_atomic_load(&zpub[0 * 512 + j], __ATOMIC_RELAXED, __HIP_MEMORY_SCOPE_AGENT);
          float zf = __hip_atomic_load(&zpub[1 * 512 + j], __ATOMIC_RELAXED, __HIP_MEMORY_SCOPE_AGENT);
          float zg = __hip_atomic_load(&zpub[2 * 512 + j], __ATOMIC_RELAXED, __HIP_MEMORY_SCOPE_AGENT);
          c = sigf(zf) * c + sigf(zi) * tanh_f(zg);
          hval = sigf(z) * tanh_f(c);
          hdec[(size_t)t * HID + j] = hval;
        }
        float hother = __shfl_xor(hval, 1);
        uint32_t* hw = (uint32_t*)(hbuf + ((t + 1) & 1) * 64);
        if (act && !(j & 1)) {
          uint32_t p = packh2(hval, hother);
          hw[j >> 1] = p;
          __hip_atomic_store(&hpub[j >> 1], p, __ATOMIC_RELAXED, __HIP_MEMORY_SCOPE_AGENT);
        }
        __threadfence();
        __syncthreads();
        if (tid == 0)
          __hip_atomic_store(&flag_h[t], 1, __ATOMIC_RELEASE, __HIP_MEMORY_SCOPE_AGENT);
      }
    }
  } else if (b == 6) {
    float* u = (float*)smem;
    if (tid < 64) u[tid] = emb_uid_w[(size_t)uid[0] * 64 + tid];
    __syncthreads();
    if (tid < HID) {
      float a = fc_user_b[tid];
      for (int k = 0; k < 64; k++) a += u[k] * fc_user_w[tid * 64 + k];
      uid_emb[tid] = a;
    }
  } else if (b < 903) {
    const int g = b - 7;
    const int chunk = g >> 5, w = g & 31;
    uint32_t* AsP = (uint32_t*)smem;
    uint32_t* WsP = AsP + 8 * 65;
    if (w < 16) {
      gemm_tile_emb(loc, tim, cid, weight, emb_tim_w, weight_cid, 0,
                    Wih_f, b_f, A_f, 1000, HIST, 1000, chunk * 64, w * 64, 0,
                    tid, AsP, WsP);
      __threadfence();
      __syncthreads();
      if (tid == 0)
        __hip_atomic_fetch_add(&cnt[chunk], 1, __ATOMIC_RELEASE, __HIP_MEMORY_SCOPE_AGENT);
    } else {
      gemm_tile_emb(loc, tim, cid, weight, emb_tim_w, weight_cid, 0,
                    Wih_b, b_b, A_b, 1000, HIST, 1000, chunk * 64, (w - 16) * 64, 1,
                    tid, AsP, WsP);
      __threadfence();
      __syncthreads();
      if (tid == 0)
        __hip_atomic_fetch_add(&cnt[32 + chunk], 1, __ATOMIC_RELEASE, __HIP_MEMORY_SCOPE_AGENT);
    }
  } else if (b < 1031) {
    const int g = b - 903;
    const int mt = g >> 5, nt = g & 31;
    uint32_t* AsP = (uint32_t*)smem;
    uint32_t* WsP = AsP + 8 * 65;
    gemm_tile_emb(loc, tim, cid, weight, emb_tim_w, weight_cid, HIST,
                  Wih_d, b_d, A_d, 2000, TGT, 2000, mt * 64, nt * 64, 0,
                  tid, AsP, WsP);
    __threadfence();
    __syncthreads();
    if (tid == 0)
      __hip_atomic_fetch_add(&cnt[64 + mt], 1, __ATOMIC_RELEASE, __HIP_MEMORY_SCOPE_AGENT);
  } else if (b < 1287) {
    const int i = b - 1031;
    float* e = (float*)smem;
    float* red = ((float*)smem) + HIST;
    const int loc_i = loc[HIST + i], tim_i = tim[HIST + i];
    for (int tab = 0; tab < 3; tab++) {
      for (int jj = tid; jj < HIST; jj += 512) {
        float v;
        if (tab == 0)      v = 1.f / pd[(size_t)loc_i * 10000 + loc[jj]];
        else if (tab == 1) v = ts[tim_i * 48 + tim[jj]];
        else               v = pct[tim_i * 300 + cid[jj]];
        e[jj] = v;
      }
      __syncthreads();
      float mx = -1e30f;
      for (int jj = tid; jj < HIST; jj += 512) mx = fmaxf(mx, e[jj]);
      red[tid] = mx; __syncthreads();
      for (int s = 256; s > 0; s >>= 1) { if (tid < s) red[tid] = fmaxf(red[tid], red[tid + s]); __syncthreads(); }
      mx = red[0]; __syncthreads();
      float sm = 0.f;
      for (int jj = tid; jj < HIST; jj += 512) sm += __expf(e[jj] - mx);
      red[tid] = sm; __syncthreads();
      for (int s = 256; s > 0; s >>= 1) { if (tid < s) red[tid] += red[tid + s]; __syncthreads(); }
      float inv = 1.f / red[0]; __syncthreads();
      for (int jj = tid; jj < HIST; jj += 512) {
        float p = __expf(e[jj] - mx) * inv;
        if (tab == 0) S1[(size_t)i * HIST + jj] = p; else S1[(size_t)i * HIST + jj] += p;
      }
      __syncthreads();
    }
    int lj = 0, tj = 0, cj = 0;
    if (tid < TGT) { lj = loc[HIST + tid]; tj = tim[HIST + tid]; cj = cid[HIST + tid]; }
    for (int tab = 0; tab < 3; tab++) {
      float v = 0.f;
      if (tid < TGT) {
        if (tab == 0)      v = 1.f / pd[(size_t)loc_i * 10000 + lj];
        else if (tab == 1) v = ts[tim_i * 48 + tj];
        else               v = pct[tim_i * 300 + cj];
        if (tid > i) v = 0.f;
        red[tid] = v;
      }
      __syncthreads();
      for (int s = 128; s > 0; s >>= 1) { if (tid < s) red[tid] = fmaxf(red[tid], red[tid + s]); __syncthreads(); }
      float mx = red[0]; __syncthreads();
      float ex = (tid < TGT) ? __expf(v - mx) : 0.f;
      if (tid < TGT) red[tid] = ex;
      __syncthreads();
      for (int s = 128; s > 0; s >>= 1) { if (tid < s) red[tid] += red[tid + s]; __syncthreads(); }
      float p = ex / red[0]; __syncthreads();
      if (tid < TGT) {
        if (tab == 0) S2[(size_t)i * TGT + tid] = p; else S2[(size_t)i * TGT + tid] += p;
      }
      __syncthreads();
    }
  } else {
    const int r0 = (b - 1287) * 16;
    for (int idx = tid; idx < 16 * 256; idx += 512) {
      int row = r0 + (idx >> 8), col = idx & 255;
      te[(size_t)row * 256 + col] = weight[(size_t)target[row] * 256 + col];
    }
  }
}

// ---------------- fused tail: k_user | cubias | nn16 x2 (R16) ----------------
__launch_bounds__(512)
__global__ void k_tail(const float* __restrict__ uid_emb, const float* __restrict__ hh,
                       float* __restrict__ cu, int* cu_flag,
                       const float* __restrict__ Wf, const float* __restrict__ bf,
                       const float* __restrict__ W2, const float* __restrict__ b2,
                       float* __restrict__ fb, float* __restrict__ fb2,
                       const float* __restrict__ S2, const float* __restrict__ hdec,
                       const float* __restrict__ S1, float* __restrict__ outb) {
  const int b = blockIdx.x;
  const int tid = threadIdx.x;
  __shared__ __align__(16) float sh[HIST + 512];
  if (b == 0) {
    float* s = sh;
    float* red = sh + HIST;
    __shared__ __align__(16) float ue[HID];
    if (tid < HID) ue[tid] = uid_emb[tid];
    __syncthreads();
    for (int t = tid; t < HIST; t += 512) {
      const float4* hr = (const float4*)(hh + (size_t)t * HID);
      const float4* uv = (const float4*)ue;
      float a = 0.f;
#pragma unroll 5
      for (int k = 0; k < 125; k++) {
        float4 h4 = hr[k], u4 = uv[k];
        a += h4.x * u4.x + h4.y * u4.y + h4.z * u4.z + h4.w * u4.w;
      }
      s[t] = a;
    }
    __syncthreads();
    float mx = -1e30f;
    for (int t = tid; t < HIST; t += 512) mx = fmaxf(mx, s[t]);
    red[tid] = mx; __syncthreads();
    for (int st = 256; st > 0; st >>= 1) { if (tid < st) red[tid] = fmaxf(red[tid], red[tid + st]); __syncthreads(); }
    mx = red[0]; __syncthreads();
    float sm = 0.f;
    for (int t = tid; t < HIST; t += 512) sm += __expf(s[t] - mx);
    red[tid] = sm; __syncthreads();
    for (int st = 256; st > 0; st >>= 1) { if (tid < st) red[tid] += red[tid + st]; __syncthreads(); }
    float inv = 1.f / red[0]; __syncthreads();
    for (int t = tid; t < HIST; t += 512) s[t] = __expf(s[t] - mx) * inv;
    __syncthreads();
    if (tid < HID) {
      float a0 = 0.f, a1 = 0.f, a2 = 0.f, a3 = 0.f;
      for (int t = 0; t < HIST; t += 4) {
        a0 += s[t]     * hh[(size_t)t * HID + tid];
        a1 += s[t + 1] * hh[(size_t)(t + 1) * HID + tid];
        a2 += s[t + 2] * hh[(size_t)(t + 2) * HID + tid];
        a3 += s[t + 3] * hh[(size_t)(t + 3) * HID + tid];
      }
      cu[tid] = (a0 + a1) + (a2 + a3);
    }
    __threadfence();
    __syncthreads();
    if (tid == 0)
      __hip_atomic_store(cu_flag, 1, __ATOMIC_RELEASE, __HIP_MEMORY_SCOPE_AGENT);
  } else if (b < 22) {
    float* cus = sh;
    if (tid == 0) spin_flag(cu_flag);
    __syncthreads();
    if (tid < 500) cus[tid] = __hip_atomic_load(&cu[tid], __ATOMIC_RELAXED, __HIP_MEMORY_SCOPE_AGENT);
    __syncthreads();
    int n = (b - 1) * 512 + tid;
    const float4* cv = (const float4*)cus;
    if (n < 10000) {
      const float4* w = (const float4*)(Wf + (size_t)n * 1500 + 1000);
      float a = bf[n];
#pragma unroll 5
      for (int k = 0; k < 125; k++) {
        float4 wv = w[k], uv = cv[k];
        a += wv.x * uv.x + wv.y * uv.y + wv.z * uv.z + wv.w * uv.w;
      }
      fb[n] = a;
    } else if (n < 10500) {
      int m = n - 10000;
      const float4* w = (const float4*)(W2 + (size_t)m * 1500 + 1000);
      float a = b2[m];
#pragma unroll 5
      for (int k = 0; k < 125; k++) {
        float4 wv = w[k], uv = cv[k];
        a += wv.x * uv.x + wv.y * uv.y + wv.z * uv.z + wv.w * uv.w;
      }
      fb2[m] = a;
    }
  } else if (b < 54) {
    const int g = b - 22;
    const int nt = g & 7, mt = g >> 3;
    uint32_t* AsP = (uint32_t*)sh;
    uint32_t* BsP = AsP + 8 * 65;
    nn_tile_fused(S2, TGT, hdec, HID, uid_emb, outb, 1000,
                  TGT, HID, TGT, mt * 64, nt * 64, tid, AsP, BsP);
  } else {
    const int g = b - 54;
    const int nt = g & 7, mt = g >> 3;
    uint32_t* AsP = (uint32_t*)sh;
    uint32_t* BsP = AsP + 8 * 65;
    nn_tile_fused(S1, HIST, hh, HID, nullptr, outb + 500, 1000,
                  TGT, HID, HIST, mt * 64, nt * 64, tid, AsP, BsP);
  }
}

// ------- merged final GEMMs: score (157 ntiles) + y1 (8 ntiles), 256 thr -------
__global__ void k_final(const float* __restrict__ A,
                        const float* __restrict__ Wf, const float* __restrict__ fb,
                        const float* __restrict__ W2, const float* __restrict__ fb2,
                        float* __restrict__ score, float* __restrict__ y1) {
  __shared__ uint32_t AsP[8][65];
  __shared__ uint32_t WsP[8][65];
  const int bx = blockIdx.x;
  const int bm = blockIdx.y * 64;
  const int tid = threadIdx.x;
  const int tx = tid & 15, ty = tid >> 4;
  const int K = 1000;
  const float* W; const float* bias; float* C; int ldc, N, bn;
  if (bx < 157) { W = Wf; bias = fb; C = score; ldc = 10000; N = 10000; bn = bx * 64; }
  else          { W = W2; bias = fb2; C = y1;   ldc = 500;   N = 500;   bn = (bx - 157) * 64; }
  float acc[4][4] = {};
  for (int k0 = 0; k0 < K; k0 += 16) {
    for (int i = tid; i < 512; i += 256) {
      int m = i & 63, kk = i >> 6;
      int gm = bm + m, gk = k0 + 2 * kk;
      float v0 = 0.f, v1 = 0.f;
      if (gm < TGT) {
        v0 = A[(size_t)gm * 1000 + gk];
        v1 = A[(size_t)gm * 1000 + gk + 1];
      }
      AsP[kk][m] = packh2(v0, v1);
    }
    for (int i = tid; i < 512; i += 256) {
      int n = i & 63, kk = i >> 6;
      int gn = bn + n, gk = k0 + 2 * kk;
      float v0 = 0.f, v1 = 0.f;
      if (gn < N) {
        v0 = W[(size_t)gn * 1500 + gk];
        v1 = W[(size_t)gn * 1500 + gk + 1];
      }
      WsP[kk][n] = packh2(v0, v1);
    }
    __syncthreads();
#pragma unroll
    for (int kk = 0; kk < 8; kk++) {
      uint32_t a0 = AsP[kk][ty * 4 + 0], a1 = AsP[kk][ty * 4 + 1], a2 = AsP[kk][ty * 4 + 2], a3 = AsP[kk][ty * 4 + 3];
      uint32_t b0 = WsP[kk][tx * 4 + 0], b1 = WsP[kk][tx * 4 + 1], b2 = WsP[kk][tx * 4 + 2], b3 = WsP[kk][tx * 4 + 3];
      acc[0][0] = fdot2(a0, b0, acc[0][0]); acc[0][1] = fdot2(a0, b1, acc[0][1]);
      acc[0][2] = fdot2(a0, b2, acc[0][2]); acc[0][3] = fdot2(a0, b3, acc[0][3]);
      acc[1][0] = fdot2(a1, b0, acc[1][0]); acc[1][1] = fdot2(a1, b1, acc[1][1]);
      acc[1][2] = fdot2(a1, b2, acc[1][2]); acc[1][3] = fdot2(a1, b3, acc[1][3]);
      acc[2][0] = fdot2(a2, b0, acc[2][0]); acc[2][1] = fdot2(a2, b1, acc[2][1]);
      acc[2][2] = fdot2(a2, b2, acc[2][2]); acc[2][3] = fdot2(a2, b3, acc[2][3]);
      acc[3][0] = fdot2(a3, b0, acc[3][0]); acc[3][1] = fdot2(a3, b1, acc[3][1]);
      acc[3][2] = fdot2(a3, b2, acc[3][2]); acc[3][3] = fdot2(a3, b3, acc[3][3]);
    }
    __syncthreads();
  }
  for (int i = 0; i < 4; i++) {
    int gm = bm + ty * 4 + i; if (gm >= TGT) continue;
    for (int j = 0; j < 4; j++) {
      int gn = bn + tx * 4 + j; if (gn >= N) continue;
      C[(size_t)gm * ldc + gn] = acc[i][j] + bias[gn];
    }
  }
}

// ---------------- in-place log-softmax ----------------
__global__ void k_logsoftmax(float* __restrict__ y) {
  const int i = blockIdx.x;
  const int tid = threadIdx.x; // 1024
  float* r = y + (size_t)i * 10000;
  __shared__ float red[1024];
  float mx = -1e30f;
  for (int j = tid; j < 10000; j += 1024) mx = fmaxf(mx, r[j]);
  red[tid] = mx; __syncthreads();
  for (int s = 512; s > 0; s >>= 1) { if (tid < s) red[tid] = fmaxf(red[tid], red[tid + s]); __syncthreads(); }
  mx = red[0]; __syncthreads();
  float sm = 0.f;
  for (int j = tid; j < 10000; j += 1024) sm += __expf(r[j] - mx);
  red[tid] = sm; __syncthreads();
  for (int s = 512; s > 0; s >>= 1) { if (tid < s) red[tid] += red[tid + s]; __syncthreads(); }
  float lse = mx + __logf(red[0]);
  __syncthreads();
  for (int j = tid; j < 10000; j += 1024) r[j] = r[j] - lse;
}

extern "C" void kernel_launch(void* const* d_in, const int* in_sizes, int n_in,
                              void* d_out, int out_size, void* d_ws, size_t ws_size,
                              hipStream_t stream) {
  (void)in_sizes; (void)n_in; (void)out_size; (void)ws_size;
  const int* loc = (const int*)d_in[0];
  const int* tim = (const int*)d_in[1];
  const int* cid = (const int*)d_in[2];
  const int* uid = (const int*)d_in[3];
  const int* target = (const int*)d_in[4];
  const float* ts = (const float*)d_in[6];
  const float* pd = (const float*)d_in[7];
  const float* pct = (const float*)d_in[8];
  const float* weight = (const float*)d_in[9];
  const float* weight_cid = (const float*)d_in[10];
  const float* emb_uid_w = (const float*)d_in[11];
  const float* emb_tim_w = (const float*)d_in[12];
  const float* enc_Wih_f = (const float*)d_in[13];
  const float* enc_Whh_f = (const float*)d_in[14];
  const float* enc_b_f = (const float*)d_in[15];
  const float* enc_Wih_b = (const float*)d_in[16];
  const float* enc_Whh_b = (const float*)d_in[17];
  const float* enc_b_b = (const float*)d_in[18];
  const float* dec_Wih = (const float*)d_in[19];
  const float* dec_Whh = (const float*)d_in[20];
  const float* dec_b = (const float*)d_in[21];
  const float* fc_user_w = (const float*)d_in[22];
  const float* fc_user_b = (const float*)d_in[23];
  const float* fc_final_w = (const float*)d_in[24];
  const float* fc_final_b = (const float*)d_in[25];
  const float* fc_final2_w = (const float*)d_in[26];
  const float* fc_final2_b = (const float*)d_in[27];

  float* score = (float*)d_out;                  // 256*10000
  float* y1 = score + (size_t)TGT * 10000;       // 256*500
  float* te = y1 + (size_t)TGT * HID;            // 256*256

  float* ws = (float*)d_ws;
  float* A_f = ws;                                // HIST*1000
  float* A_b = A_f + (size_t)HIST * 1000;         // HIST*1000
  float* A_d = A_b + (size_t)HIST * 1000;         // TGT*2000
  float* hh = A_d + (size_t)TGT * 2000;           // HIST*500
  float* hdec = hh + (size_t)HIST * HID;          // TGT*500
  float* S1 = hdec + (size_t)TGT * HID;           // TGT*HIST
  float* S2 = S1 + (size_t)TGT * HIST;            // TGT*TGT
  float* outb = S2 + (size_t)TGT * TGT;           // TGT*1000
  float* cu = outb + (size_t)TGT * 1000;          // 512
  float* fb = cu + 512;                           // 10016
  float* fb2 = fb + 10016;                        // 512
  float* uid_emb = fb2 + 512;                     // 512
  float* zpub = uid_emb + 512;                    // 3*512
  uint32_t* hpub = (uint32_t*)(zpub + 3 * 512);   // 256
  int* flag_z = (int*)(hpub + 256);               // 3*256
  int* flag_h = flag_z + 3 * TGT;                 // 256
  int* cnt = flag_h + TGT;                        // 96
  int* cu_flag = cnt + 96;                        // 1
  const int n_flags = 4 * TGT + 96 + 1;

  hipMemsetAsync(flag_z, 0, n_flags * sizeof(int), stream);

  k_lstm<<<dim3(1303), dim3(512), 0, stream>>>(A_f, A_b, A_d,
                                               enc_Wih_f, enc_b_f, enc_Wih_b, enc_b_b,
                                               dec_Wih, dec_b,
                                               enc_Whh_f, enc_Whh_b, dec_Whh,
                                               hh, hdec, zpub, hpub, flag_z, flag_h, cnt,
                                               loc, tim, cid, target,
                                               weight, emb_tim_w, weight_cid,
                                               ts, pd, pct, S1, S2,
                                               uid, emb_uid_w, fc_user_w, fc_user_b,
                                               uid_emb, te);

  k_tail<<<dim3(86), dim3(512), 0, stream>>>(uid_emb, hh, cu, cu_flag,
                                             fc_final_w, fc_final_b,
                                             fc_final2_w, fc_final2_b, fb, fb2,
                                             S2, hdec, S1, outb);

  k_final<<<dim3(165, 4), dim3(256), 0, stream>>>(outb, fc_final_w, fb,
                                                  fc_final2_w, fb2, score, y1);

  k_logsoftmax<<<dim3(TGT), dim3(1024), 0, stream>>>(score);
}